// Round 7
// baseline (470.527 us; speedup 1.0000x reference)
//
#include <hip/hip_runtime.h>
#include <hip/hip_cooperative_groups.h>

namespace cg = cooperative_groups;

#ifndef __has_builtin
#define __has_builtin(x) 0
#endif

__device__ __forceinline__ float fexp2(float x) {
#if __has_builtin(__builtin_amdgcn_exp2f)
    return __builtin_amdgcn_exp2f(x);
#else
    return exp2f(x);
#endif
}
__device__ __forceinline__ float frcp(float x) {
#if __has_builtin(__builtin_amdgcn_rcpf)
    return __builtin_amdgcn_rcpf(x);
#else
    return 1.0f / x;
#endif
}

constexpr int TT = 32;      // directions T
constexpr int SS = 32;      // steps S
constexpr int BB = 64;      // graphs B
constexpr int NPART = 256;  // hist/scatter partitions
constexpr int GRID = 1024;  // cooperative grid (4 blocks/CU, safely co-resident)
constexpr int ZB = 16;      // out-zeroing blocks
constexpr float FL = 50.0f * 1.44269504088896340736f;  // steepness * log2(e)
constexpr float QS = 65536.0f;                          // fixed-point scale 2^16
constexpr float IQS = 1.0f / 65536.0f;

// ---- ECT core: window-3 sigmoid + histogram suffix, u32 fixed-point LDS atomics ----
// Thread owns (point-slot pr = tid>>5, t = tid&31); heights read from nh rows (coalesced).
__device__ __forceinline__ void ect_core(
    const float* __restrict__ nh, const float* __restrict__ lin,
    const int* __restrict__ ssrc, const int* __restrict__ sdst,
    bool edge, int lo, int hi, int g, float sign, float* __restrict__ out)
{
    __shared__ unsigned accS[TT][SS + 1];
    __shared__ unsigned cntS[TT][SS + 1];
    __shared__ unsigned part[TT][9];
    for (int i = threadIdx.x; i < TT * (SS + 1); i += 256) {
        ((unsigned*)accS)[i] = 0u;
        ((unsigned*)cntS)[i] = 0u;
    }
    const int t = threadIdx.x & 31;
    const int pr = threadIdx.x >> 5;
    const float l0 = lin[0];
    const float dS = lin[1] - l0;
    const float invD = frcp(dS);
    const float fld = FL * dS;                 // ~5.12 exp2-units per bin
    const float pm1 = fexp2(fld), pp1 = fexp2(-fld);
    __syncthreads();

#pragma unroll 4
    for (int base = lo; base < hi; base += 8) {
        const int p = base + pr;
        if (p < hi) {
            float h;
            if (edge) {
                const int sn = ssrc[p], dn = sdst[p];
                h = fmaxf(nh[(size_t)sn * TT + t], nh[(size_t)dn * TT + t]);
            } else {
                h = nh[(size_t)p * TT + t];
            }
            const float hl0 = h - l0;
            float fj = rintf(hl0 * invD);
            fj = fminf(34.f, fmaxf(-2.f, fj));
            const int j = (int)fj;
            const float delta = fmaf(-fj, dS, hl0);   // h - l_j
            const float ucen = fexp2(FL * delta);     // in [0.17, 5.9] when unclamped
            const unsigned q0 = __float2uint_rn(QS * frcp(fmaf(ucen, pm1, 1.f))); // s=j-1
            const unsigned q1 = __float2uint_rn(QS * frcp(1.f + ucen));           // s=j
            const unsigned q2 = __float2uint_rn(QS * frcp(fmaf(ucen, pp1, 1.f))); // s=j+1
            const int b = j + 2;
            if (b < SS) atomicAdd(&cntS[t][b], 1u);
            if (1 <= j && j <= SS) atomicAdd(&accS[t][j - 1], q0);
            if (0 <= j && j < SS)  atomicAdd(&accS[t][j], q1);
            if (-1 <= j && j < SS - 1) atomicAdd(&accS[t][j + 1], q2);
        }
    }
    __syncthreads();
    // two-level scan: thread (t, q=pr) owns s in [4q, 4q+4)
    const unsigned c0 = cntS[t][4 * pr], c1 = cntS[t][4 * pr + 1];
    const unsigned c2 = cntS[t][4 * pr + 2], c3 = cntS[t][4 * pr + 3];
    part[t][pr + 1] = c0 + c1 + c2 + c3;
    if (pr == 0) part[t][0] = 0u;
    __syncthreads();
    if (pr == 0) {
        unsigned r = 0u;
#pragma unroll
        for (int q = 1; q <= 8; ++q) { r += part[t][q]; part[t][q] = r; }
    }
    __syncthreads();
    unsigned run = part[t][pr];
    float* o = out + (size_t)g * SS * TT;
    run += c0;
    atomicAdd(&o[(4 * pr + 0) * TT + t], sign * fmaf((float)accS[t][4 * pr + 0], IQS, (float)run));
    run += c1;
    atomicAdd(&o[(4 * pr + 1) * TT + t], sign * fmaf((float)accS[t][4 * pr + 1], IQS, (float)run));
    run += c2;
    atomicAdd(&o[(4 * pr + 2) * TT + t], sign * fmaf((float)accS[t][4 * pr + 2], IQS, (float)run));
    run += c3;
    atomicAdd(&o[(4 * pr + 3) * TT + t], sign * fmaf((float)accS[t][4 * pr + 3], IQS, (float)run));
}

// ---- single cooperative kernel: A(zero|starts|hist|nh) sync B(scatter|node-ect) sync C(edge-ect) ----
__global__ __launch_bounds__(256) void fused_k(
    const float* __restrict__ x, const float* __restrict__ v,
    const float* __restrict__ lin,
    const int* __restrict__ src, const int* __restrict__ dst,
    const int* __restrict__ batch, int N, int E,
    int* __restrict__ starts, int* __restrict__ offs, int* __restrict__ hist,
    int* __restrict__ ssrc, int* __restrict__ sdst,
    float* __restrict__ nh, float* __restrict__ out)
{
    const int bid = blockIdx.x;
    const int tid = threadIdx.x;
    const int sB = (N + 255) / 256;          // starts blocks (196 at N=50000)

    // ---------------- Phase A ----------------
    if (bid < ZB) {
        float4* o4 = (float4*)out;
        for (int i = bid * 256 + tid; i < BB * SS * TT / 4; i += ZB * 256)
            o4[i] = float4{0.f, 0.f, 0.f, 0.f};
    } else if (bid < ZB + sB) {
        const int n = (bid - ZB) * 256 + tid;
        if (n < N) {
            const int g = batch[n];
            const int gp = (n == 0) ? -1 : batch[n - 1];
            for (int g2 = gp + 1; g2 <= g; ++g2) starts[g2] = n;
            if (n == N - 1)
                for (int g2 = g + 1; g2 <= BB; ++g2) starts[g2] = N;
        }
    } else if (bid < ZB + sB + NPART) {
        const int b = bid - ZB - sB;
        __shared__ int hsh[BB];
        if (tid < BB) hsh[tid] = 0;
        __syncthreads();
        const int per = (E + NPART - 1) / NPART;
        const int lo = b * per, hi = min(E, lo + per);
        for (int e = lo + tid; e < hi; e += 256)
            atomicAdd(&hsh[batch[src[e]]], 1);
        __syncthreads();
        if (tid < BB) hist[b * BB + tid] = hsh[tid];
    } else {
        // nh precompute: nh[p][t] = dot(x_p, v_t)
        const int nb0 = ZB + sB + NPART;
        const int nblocks = GRID - nb0;
        const int t = tid & 31, pr = tid >> 5;
        const float v0 = v[t], v1 = v[TT + t], v2 = v[2 * TT + t];
        const int groups = (N + 7) / 8;
        for (int grp = bid - nb0; grp < groups; grp += nblocks) {
            const int p = grp * 8 + pr;
            if (p < N)
                nh[(size_t)p * TT + t] =
                    fmaf(x[3 * p], v0, fmaf(x[3 * p + 1], v1, x[3 * p + 2] * v2));
        }
    }
    __threadfence();
    cg::this_grid().sync();

    // ---------------- Phase B ----------------
    if (bid < NPART) {
        // scatter: per-block base = graph offset + sum of earlier partitions' hist
        __shared__ int lcur[BB];
        __shared__ int stot[BB];
        if (tid < BB) {
            int accb = 0, tot = 0;
            for (int b = 0; b < NPART; ++b) {
                const int hv = hist[b * BB + tid];
                accb += (b < bid) ? hv : 0;
                tot += hv;
            }
            lcur[tid] = accb;
            stot[tid] = tot;
        }
        __syncthreads();
        if (tid == 0) {
            int run = 0;
            for (int i = 0; i < BB; ++i) { const int tv = stot[i]; stot[i] = run; run += tv; }
            if (bid == 0) offs[BB] = run;
        }
        __syncthreads();
        if (tid < BB) {
            lcur[tid] += stot[tid];
            if (bid == 0) offs[tid] = stot[tid];
        }
        __syncthreads();
        const int per = (E + NPART - 1) / NPART;
        const int lo = bid * per, hi = min(E, lo + per);
        for (int e = lo + tid; e < hi; e += 256) {
            const int s = src[e], d = dst[e];
            const int pos = atomicAdd(&lcur[batch[s]], 1);
            ssrc[pos] = s;
            sdst[pos] = d;
        }
    } else {
        const int CPBn = (GRID - NPART) / BB;   // 12
        const int b2 = bid - NPART;
        const int g = b2 / CPBn, c = b2 % CPBn;
        const int s0 = starts[g], s1 = starts[g + 1];
        const int chunk = (s1 - s0 + CPBn - 1) / CPBn;
        const int lo = s0 + c * chunk, hi = min(s1, lo + chunk);
        ect_core(nh, lin, nullptr, nullptr, false, lo, hi, g, 1.0f, out);
    }
    __threadfence();
    cg::this_grid().sync();

    // ---------------- Phase C ----------------
    {
        const int CPBe = GRID / BB;             // 16
        const int g = bid / CPBe, c = bid % CPBe;
        const int s0 = offs[g], s1 = offs[g + 1];
        const int chunk = (s1 - s0 + CPBe - 1) / CPBe;
        const int lo = s0 + c * chunk, hi = min(s1, lo + chunk);
        ect_core(nh, lin, ssrc, sdst, true, lo, hi, g, -1.0f, out);
    }
}

extern "C" void kernel_launch(void* const* d_in, const int* in_sizes, int n_in,
                              void* d_out, int out_size, void* d_ws, size_t ws_size,
                              hipStream_t stream) {
    const float* x   = (const float*)d_in[0];
    const float* v   = (const float*)d_in[1];
    const float* lin = (const float*)d_in[2];
    const int* edge_index = (const int*)d_in[3];
    const int* batch = (const int*)d_in[4];

    int N = in_sizes[0] / 3;
    int E = in_sizes[3] / 2;
    const int* src = edge_index;       // edge_index[0][:]
    const int* dst = edge_index + E;   // edge_index[1][:]
    float* out = (float*)d_out;

    char* ws = (char*)d_ws;
    int* starts = (int*)ws;                                  // 65 ints
    int* offs   = (int*)(ws + 512);                          // 65 ints
    int* hist   = (int*)(ws + 4096);                         // NPART*BB ints (64 KB)
    int* ssrc   = (int*)(ws + 4096 + NPART * BB * 4);        // E ints
    int* sdst   = ssrc + E;                                  // E ints
    float* nh   = (float*)(ws + 4096 + NPART * BB * 4 +
                           ((2 * (size_t)E * 4 + 255) / 256) * 256);  // N*32 floats

    void* args[] = {(void*)&x, (void*)&v, (void*)&lin, (void*)&src, (void*)&dst,
                    (void*)&batch, (void*)&N, (void*)&E,
                    (void*)&starts, (void*)&offs, (void*)&hist,
                    (void*)&ssrc, (void*)&sdst, (void*)&nh, (void*)&out};
    hipLaunchCooperativeKernel((void*)fused_k, dim3(GRID), dim3(256), args, 0, stream);
}

// Round 8
// 47.485 us; speedup vs baseline: 9.9089x; 9.9089x over previous
//
#include <hip/hip_runtime.h>

#ifndef __has_builtin
#define __has_builtin(x) 0
#endif

__device__ __forceinline__ float fexp2(float x) {
#if __has_builtin(__builtin_amdgcn_exp2f)
    return __builtin_amdgcn_exp2f(x);
#else
    return exp2f(x);
#endif
}
__device__ __forceinline__ float frcp(float x) {
#if __has_builtin(__builtin_amdgcn_rcpf)
    return __builtin_amdgcn_rcpf(x);
#else
    return 1.0f / x;
#endif
}

constexpr int TT = 32;    // directions T
constexpr int SS = 32;    // steps S
constexpr int BB = 64;    // graphs B
constexpr int NB = 64;    // partition blocks for edge sort
constexpr int CPB_N = 8;  // chunks per graph, node part
constexpr int CPB_E = 16; // chunks per graph, edge part
constexpr int NHB = 256;  // nh precompute blocks
constexpr float FL = 50.0f * 1.44269504088896340736f;  // steepness * log2(e)
constexpr float QS = 65536.0f;                          // fixed-point scale 2^16
constexpr float IQS = 1.0f / 65536.0f;

// ---- prep: bounds + hist + out-zero + nh[N][32] precompute ----
__global__ __launch_bounds__(256) void prep_k(
    const float* __restrict__ x, const float* __restrict__ v,
    const int* __restrict__ batch, const int* __restrict__ src,
    int N, int E, int nB,
    int* __restrict__ starts, int* __restrict__ hist,
    float* __restrict__ nh, float* __restrict__ out)
{
    if ((int)blockIdx.x < nB) {
        const int n = blockIdx.x * 256 + threadIdx.x;
        if (n >= N) return;
        const int g = batch[n];
        const int gp = (n == 0) ? -1 : batch[n - 1];
        for (int g2 = gp + 1; g2 <= g; ++g2) starts[g2] = n;
        if (n == N - 1)
            for (int g2 = g + 1; g2 <= BB; ++g2) starts[g2] = N;
    } else if ((int)blockIdx.x < nB + NB) {
        const int b = blockIdx.x - nB;      // 0..NB-1
        float4* o4 = (float4*)(out + (size_t)b * SS * TT);
        o4[threadIdx.x] = float4{0.f, 0.f, 0.f, 0.f};
        __shared__ int h[BB];
        if (threadIdx.x < BB) h[threadIdx.x] = 0;
        __syncthreads();
        const int per = (E + NB - 1) / NB;
        const int lo = b * per, hi = min(E, lo + per);
        for (int e = lo + threadIdx.x; e < hi; e += 256)
            atomicAdd(&h[batch[src[e]]], 1);
        __syncthreads();
        if (threadIdx.x < BB) hist[b * BB + threadIdx.x] = h[threadIdx.x];
    } else {
        // nh precompute: nh[p][t] = dot(x_p, v_t), 8 points per block-iteration
        const int b = blockIdx.x - nB - NB;
        const int t = threadIdx.x & 31, pr = threadIdx.x >> 5;
        const float v0 = v[t], v1 = v[TT + t], v2 = v[2 * TT + t];
        const int groups = (N + 7) / 8;
        for (int grp = b; grp < groups; grp += NHB) {
            const int p = grp * 8 + pr;
            if (p < N)
                nh[(p << 5) + t] =
                    fmaf(x[3 * p], v0, fmaf(x[3 * p + 1], v1, x[3 * p + 2] * v2));
        }
    }
}

// ---- ECT core: window-3 sigmoid + histogram suffix, u32 fixed-point LDS atomics ----
// Thread owns (point-slot pr = tid>>5, t = tid&31); heights read from nh rows (coalesced).
__device__ __forceinline__ void ect_core(
    const float* __restrict__ nh, const float* __restrict__ lin,
    const int2* __restrict__ epair,
    bool edge, int lo, int hi, int g, float sign, float* __restrict__ out)
{
    __shared__ unsigned accS[TT][SS + 1];
    __shared__ unsigned cntS[TT][SS + 1];
    __shared__ unsigned part[TT][9];
    for (int i = threadIdx.x; i < TT * (SS + 1); i += 256) {
        ((unsigned*)accS)[i] = 0u;
        ((unsigned*)cntS)[i] = 0u;
    }
    const int t = threadIdx.x & 31;
    const int pr = threadIdx.x >> 5;
    const float l0 = lin[0];
    const float dS = lin[1] - l0;
    const float invD = frcp(dS);
    const float fld = FL * dS;                 // ~5.12 exp2-units per bin
    const float pm1 = fexp2(fld), pp1 = fexp2(-fld);
    __syncthreads();

#pragma unroll 4
    for (int base = lo; base < hi; base += 8) {
        const int p = base + pr;
        if (p < hi) {
            float h;
            if (edge) {
                const int2 ed = epair[p];
                h = fmaxf(nh[(ed.x << 5) + t], nh[(ed.y << 5) + t]);
            } else {
                h = nh[(p << 5) + t];
            }
            const float hl0 = h - l0;
            float fj = rintf(hl0 * invD);
            fj = fminf(34.f, fmaxf(-2.f, fj));
            const int j = (int)fj;
            const float delta = fmaf(-fj, dS, hl0);   // h - l_j
            const float ucen = fexp2(FL * delta);     // in [0.17, 5.9] when unclamped
            const unsigned q0 = __float2uint_rn(QS * frcp(fmaf(ucen, pm1, 1.f))); // s=j-1
            const unsigned q1 = __float2uint_rn(QS * frcp(1.f + ucen));           // s=j
            const unsigned q2 = __float2uint_rn(QS * frcp(fmaf(ucen, pp1, 1.f))); // s=j+1
            const int b = j + 2;
            if (b < SS) atomicAdd(&cntS[t][b], 1u);
            if (1 <= j && j <= SS) atomicAdd(&accS[t][j - 1], q0);
            if (0 <= j && j < SS)  atomicAdd(&accS[t][j], q1);
            if (-1 <= j && j < SS - 1) atomicAdd(&accS[t][j + 1], q2);
        }
    }
    __syncthreads();
    // two-level scan: thread (t, q=pr) owns s in [4q, 4q+4)
    const unsigned c0 = cntS[t][4 * pr], c1 = cntS[t][4 * pr + 1];
    const unsigned c2 = cntS[t][4 * pr + 2], c3 = cntS[t][4 * pr + 3];
    part[t][pr + 1] = c0 + c1 + c2 + c3;
    if (pr == 0) part[t][0] = 0u;
    __syncthreads();
    if (pr == 0) {
        unsigned r = 0u;
#pragma unroll
        for (int q = 1; q <= 8; ++q) { r += part[t][q]; part[t][q] = r; }
    }
    __syncthreads();
    unsigned run = part[t][pr];
    float* o = out + (size_t)g * SS * TT;
    run += c0;
    atomicAdd(&o[(4 * pr + 0) * TT + t], sign * fmaf((float)accS[t][4 * pr + 0], IQS, (float)run));
    run += c1;
    atomicAdd(&o[(4 * pr + 1) * TT + t], sign * fmaf((float)accS[t][4 * pr + 1], IQS, (float)run));
    run += c2;
    atomicAdd(&o[(4 * pr + 2) * TT + t], sign * fmaf((float)accS[t][4 * pr + 2], IQS, (float)run));
    run += c3;
    atomicAdd(&o[(4 * pr + 3) * TT + t], sign * fmaf((float)accS[t][4 * pr + 3], IQS, (float)run));
}

// ---- k2: scatter blocks (0..NB-1) overlapped with node-ect blocks ----
__global__ __launch_bounds__(256) void mid_k(
    const float* __restrict__ nh, const float* __restrict__ lin,
    const int* __restrict__ src, const int* __restrict__ dst,
    const int* __restrict__ batch, int E,
    const int* __restrict__ hist, int* __restrict__ offs,
    int2* __restrict__ epair,
    const int* __restrict__ starts, float* __restrict__ out)
{
    if ((int)blockIdx.x < NB) {
        __shared__ int lcur[BB];
        __shared__ int stot[BB];
        const int tid = threadIdx.x;
        if (tid < BB) {
            int accb = 0, tot = 0;
            for (int b = 0; b < NB; ++b) {
                const int hv = hist[b * BB + tid];
                accb += (b < (int)blockIdx.x) ? hv : 0;
                tot += hv;
            }
            lcur[tid] = accb;
            stot[tid] = tot;
        }
        __syncthreads();
        if (tid == 0) {
            int run = 0;
            for (int i = 0; i < BB; ++i) { const int tv = stot[i]; stot[i] = run; run += tv; }
            if (blockIdx.x == 0) offs[BB] = run;
        }
        __syncthreads();
        if (tid < BB) {
            lcur[tid] += stot[tid];
            if (blockIdx.x == 0) offs[tid] = stot[tid];
        }
        __syncthreads();
        const int per = (E + NB - 1) / NB;
        const int lo = blockIdx.x * per, hi = min(E, lo + per);
        for (int e = lo + tid; e < hi; e += 256) {
            const int s = src[e], d = dst[e];
            const int pos = atomicAdd(&lcur[batch[s]], 1);
            epair[pos] = int2{s, d};
        }
    } else {
        const int bid = blockIdx.x - NB;
        const int g = bid / CPB_N, c = bid % CPB_N;
        const int s0 = starts[g], s1 = starts[g + 1];
        const int chunk = (s1 - s0 + CPB_N - 1) / CPB_N;
        const int lo = s0 + c * chunk;
        const int hi = min(s1, lo + chunk);
        ect_core(nh, lin, nullptr, false, lo, hi, g, 1.0f, out);
    }
}

// ---- k3: edge-ect only ----
__global__ __launch_bounds__(256) void edge_k(
    const float* __restrict__ nh, const float* __restrict__ lin,
    const int2* __restrict__ epair,
    const int* __restrict__ offs, float* __restrict__ out)
{
    const int g = blockIdx.x / CPB_E, c = blockIdx.x % CPB_E;
    const int s0 = offs[g], s1 = offs[g + 1];
    const int chunk = (s1 - s0 + CPB_E - 1) / CPB_E;
    const int lo = s0 + c * chunk;
    const int hi = min(s1, lo + chunk);
    ect_core(nh, lin, epair, true, lo, hi, g, -1.0f, out);
}

extern "C" void kernel_launch(void* const* d_in, const int* in_sizes, int n_in,
                              void* d_out, int out_size, void* d_ws, size_t ws_size,
                              hipStream_t stream) {
    const float* x   = (const float*)d_in[0];
    const float* v   = (const float*)d_in[1];
    const float* lin = (const float*)d_in[2];
    const int* edge_index = (const int*)d_in[3];
    const int* batch = (const int*)d_in[4];

    const int N = in_sizes[0] / 3;
    const int E = in_sizes[3] / 2;
    const int* src = edge_index;       // edge_index[0][:]
    const int* dst = edge_index + E;   // edge_index[1][:]
    float* out = (float*)d_out;

    char* ws = (char*)d_ws;
    int* starts = (int*)ws;                                   // 65 ints
    int* offs   = (int*)(ws + 512);                           // 65 ints
    int* hist   = (int*)(ws + 1024);                          // NB*BB ints
    int2* epair = (int2*)(ws + 65536);                        // E int2
    float* nh   = (float*)(ws + 65536 +
                           (((size_t)E * 8 + 255) / 256) * 256);  // N*32 floats

    const int nB = (N + 255) / 256;
    prep_k<<<nB + NB + NHB, 256, 0, stream>>>(x, v, batch, src, N, E, nB,
                                              starts, hist, nh, out);
    mid_k<<<NB + BB * CPB_N, 256, 0, stream>>>(nh, lin, src, dst, batch, E,
                                               hist, offs, epair, starts, out);
    edge_k<<<BB * CPB_E, 256, 0, stream>>>(nh, lin, epair, offs, out);
}

// Round 9
// 34.342 us; speedup vs baseline: 13.7014x; 1.3827x over previous
//
#include <hip/hip_runtime.h>

#ifndef __has_builtin
#define __has_builtin(x) 0
#endif

__device__ __forceinline__ float fexp2(float x) {
#if __has_builtin(__builtin_amdgcn_exp2f)
    return __builtin_amdgcn_exp2f(x);
#else
    return exp2f(x);
#endif
}
__device__ __forceinline__ float frcp(float x) {
#if __has_builtin(__builtin_amdgcn_rcpf)
    return __builtin_amdgcn_rcpf(x);
#else
    return 1.0f / x;
#endif
}

constexpr int TT = 32;    // directions T
constexpr int SS = 32;    // steps S
constexpr int BB = 64;    // graphs B
constexpr int NB = 64;    // partition blocks for edge sort
constexpr int CPB_N = 8;  // chunks per graph, node part
constexpr int CPB_E = 16; // chunks per graph, edge part
constexpr float FL = 50.0f * 1.44269504088896340736f;  // steepness * log2(e)
constexpr float QS = 65536.0f;                          // fixed-point scale 2^16
constexpr float IQS = 1.0f / 65536.0f;

// ---- prep: bounds + out-zero + edge hist (also emits ge[e] = graph of edge) ----
__global__ __launch_bounds__(256) void prep_k(
    const int* __restrict__ batch, const int* __restrict__ src,
    int N, int E, int nB,
    int* __restrict__ starts, int* __restrict__ hist,
    int* __restrict__ ge, float* __restrict__ out)
{
    if ((int)blockIdx.x < nB) {
        const int n = blockIdx.x * 256 + threadIdx.x;
        if (n >= N) return;
        const int g = batch[n];
        const int gp = (n == 0) ? -1 : batch[n - 1];
        for (int g2 = gp + 1; g2 <= g; ++g2) starts[g2] = n;
        if (n == N - 1)
            for (int g2 = g + 1; g2 <= BB; ++g2) starts[g2] = N;
    } else {
        const int b = blockIdx.x - nB;      // 0..NB-1
        float4* o4 = (float4*)(out + (size_t)b * SS * TT);
        o4[threadIdx.x] = float4{0.f, 0.f, 0.f, 0.f};
        __shared__ int h[BB];
        if (threadIdx.x < BB) h[threadIdx.x] = 0;
        __syncthreads();
        const int per = (E + NB - 1) / NB;
        const int lo = b * per, hi = min(E, lo + per);
        for (int e = lo + threadIdx.x; e < hi; e += 256) {
            const int g = batch[src[e]];
            ge[e] = g;
            atomicAdd(&h[g], 1);
        }
        __syncthreads();
        if (threadIdx.x < BB) hist[b * BB + threadIdx.x] = h[threadIdx.x];
    }
}

// ---- ECT core: window-3 sigmoid + histogram suffix, u32 LDS atomics ----
// Depth-4 software pipeline: 4 independent height-load chains in flight,
// then 4 compute+accumulate stages. All pipeline indices compile-time.
__device__ __forceinline__ void ect_core(
    const float* __restrict__ x, const float* __restrict__ v,
    const float* __restrict__ lin, const int2* __restrict__ epair,
    bool edge, int lo, int hi, int g, float sign, float* __restrict__ out)
{
    __shared__ unsigned accS[TT][SS + 1];
    __shared__ unsigned cntS[TT][SS + 1];
    __shared__ unsigned part[TT][9];
    for (int i = threadIdx.x; i < TT * (SS + 1); i += 256) {
        ((unsigned*)accS)[i] = 0u;
        ((unsigned*)cntS)[i] = 0u;
    }
    const int t = threadIdx.x & 31;
    const int pr = threadIdx.x >> 5;
    const float v0 = v[t], v1 = v[TT + t], v2 = v[2 * TT + t];
    const float l0 = lin[0];
    const float dS = lin[1] - l0;
    const float invD = frcp(dS);
    const float fld = FL * dS;                 // ~5.12 exp2-units per bin
    const float pm1 = fexp2(fld), pp1 = fexp2(-fld);
    __syncthreads();

    for (int base = lo; base < hi; base += 32) {
        float hv0 = 0.f, hv1 = 0.f, hv2 = 0.f, hv3 = 0.f;
        const int p0 = base + pr, p1 = base + 8 + pr;
        const int p2 = base + 16 + pr, p3 = base + 24 + pr;
        // stage 1: issue all height loads (independent chains)
        if (edge) {
            if (p0 < hi) { const int2 ed = epair[p0];
                hv0 = fmaxf(fmaf(x[3*ed.x], v0, fmaf(x[3*ed.x+1], v1, x[3*ed.x+2]*v2)),
                            fmaf(x[3*ed.y], v0, fmaf(x[3*ed.y+1], v1, x[3*ed.y+2]*v2))); }
            if (p1 < hi) { const int2 ed = epair[p1];
                hv1 = fmaxf(fmaf(x[3*ed.x], v0, fmaf(x[3*ed.x+1], v1, x[3*ed.x+2]*v2)),
                            fmaf(x[3*ed.y], v0, fmaf(x[3*ed.y+1], v1, x[3*ed.y+2]*v2))); }
            if (p2 < hi) { const int2 ed = epair[p2];
                hv2 = fmaxf(fmaf(x[3*ed.x], v0, fmaf(x[3*ed.x+1], v1, x[3*ed.x+2]*v2)),
                            fmaf(x[3*ed.y], v0, fmaf(x[3*ed.y+1], v1, x[3*ed.y+2]*v2))); }
            if (p3 < hi) { const int2 ed = epair[p3];
                hv3 = fmaxf(fmaf(x[3*ed.x], v0, fmaf(x[3*ed.x+1], v1, x[3*ed.x+2]*v2)),
                            fmaf(x[3*ed.y], v0, fmaf(x[3*ed.y+1], v1, x[3*ed.y+2]*v2))); }
        } else {
            if (p0 < hi) hv0 = fmaf(x[3*p0], v0, fmaf(x[3*p0+1], v1, x[3*p0+2]*v2));
            if (p1 < hi) hv1 = fmaf(x[3*p1], v0, fmaf(x[3*p1+1], v1, x[3*p1+2]*v2));
            if (p2 < hi) hv2 = fmaf(x[3*p2], v0, fmaf(x[3*p2+1], v1, x[3*p2+2]*v2));
            if (p3 < hi) hv3 = fmaf(x[3*p3], v0, fmaf(x[3*p3+1], v1, x[3*p3+2]*v2));
        }
        // stage 2: compute + accumulate
#pragma unroll
        for (int k = 0; k < 4; ++k) {
            const int p = base + 8 * k + pr;
            if (p >= hi) break;
            const float h = (k == 0) ? hv0 : (k == 1) ? hv1 : (k == 2) ? hv2 : hv3;
            const float hl0 = h - l0;
            float fj = rintf(hl0 * invD);
            fj = fminf(34.f, fmaxf(-2.f, fj));
            const int j = (int)fj;
            const float delta = fmaf(-fj, dS, hl0);   // h - l_j
            const float ucen = fexp2(FL * delta);     // in [0.17, 5.9] when unclamped
            const unsigned q0 = __float2uint_rn(QS * frcp(fmaf(ucen, pm1, 1.f))); // s=j-1
            const unsigned q1 = __float2uint_rn(QS * frcp(1.f + ucen));           // s=j
            const unsigned q2 = __float2uint_rn(QS * frcp(fmaf(ucen, pp1, 1.f))); // s=j+1
            const int b = j + 2;
            if (b < SS) atomicAdd(&cntS[t][b], 1u);
            if (1 <= j && j <= SS) atomicAdd(&accS[t][j - 1], q0);
            if (0 <= j && j < SS)  atomicAdd(&accS[t][j], q1);
            if (-1 <= j && j < SS - 1) atomicAdd(&accS[t][j + 1], q2);
        }
    }
    __syncthreads();
    // two-level scan: thread (t, q=pr) owns s in [4q, 4q+4)
    const unsigned c0 = cntS[t][4 * pr], c1 = cntS[t][4 * pr + 1];
    const unsigned c2 = cntS[t][4 * pr + 2], c3 = cntS[t][4 * pr + 3];
    part[t][pr + 1] = c0 + c1 + c2 + c3;
    if (pr == 0) part[t][0] = 0u;
    __syncthreads();
    if (pr == 0) {
        unsigned r = 0u;
#pragma unroll
        for (int q = 1; q <= 8; ++q) { r += part[t][q]; part[t][q] = r; }
    }
    __syncthreads();
    unsigned run = part[t][pr];
    float* o = out + (size_t)g * SS * TT;
    run += c0;
    atomicAdd(&o[(4 * pr + 0) * TT + t], sign * fmaf((float)accS[t][4 * pr + 0], IQS, (float)run));
    run += c1;
    atomicAdd(&o[(4 * pr + 1) * TT + t], sign * fmaf((float)accS[t][4 * pr + 1], IQS, (float)run));
    run += c2;
    atomicAdd(&o[(4 * pr + 2) * TT + t], sign * fmaf((float)accS[t][4 * pr + 2], IQS, (float)run));
    run += c3;
    atomicAdd(&o[(4 * pr + 3) * TT + t], sign * fmaf((float)accS[t][4 * pr + 3], IQS, (float)run));
}

// ---- k2: scatter blocks (0..NB-1, reading precomputed ge) ∥ node-ect blocks ----
__global__ __launch_bounds__(256) void mid_k(
    const float* __restrict__ x, const float* __restrict__ v,
    const float* __restrict__ lin,
    const int* __restrict__ src, const int* __restrict__ dst,
    const int* __restrict__ ge, int E,
    const int* __restrict__ hist, int* __restrict__ offs,
    int2* __restrict__ epair,
    const int* __restrict__ starts, float* __restrict__ out)
{
    if ((int)blockIdx.x < NB) {
        __shared__ int lcur[BB];
        __shared__ int stot[BB];
        const int tid = threadIdx.x;
        if (tid < BB) {
            int accb = 0, tot = 0;
            for (int b = 0; b < NB; ++b) {
                const int hv = hist[b * BB + tid];
                accb += (b < (int)blockIdx.x) ? hv : 0;
                tot += hv;
            }
            lcur[tid] = accb;
            stot[tid] = tot;
        }
        __syncthreads();
        if (tid == 0) {
            int run = 0;
            for (int i = 0; i < BB; ++i) { const int tv = stot[i]; stot[i] = run; run += tv; }
            if (blockIdx.x == 0) offs[BB] = run;
        }
        __syncthreads();
        if (tid < BB) {
            lcur[tid] += stot[tid];
            if (blockIdx.x == 0) offs[tid] = stot[tid];
        }
        __syncthreads();
        const int per = (E + NB - 1) / NB;
        const int lo = blockIdx.x * per, hi = min(E, lo + per);
        for (int e = lo + tid; e < hi; e += 256) {
            const int pos = atomicAdd(&lcur[ge[e]], 1);
            epair[pos] = int2{src[e], dst[e]};
        }
    } else {
        const int bid = blockIdx.x - NB;
        const int g = bid / CPB_N, c = bid % CPB_N;
        const int s0 = starts[g], s1 = starts[g + 1];
        const int chunk = (s1 - s0 + CPB_N - 1) / CPB_N;
        const int lo = s0 + c * chunk;
        const int hi = min(s1, lo + chunk);
        ect_core(x, v, lin, nullptr, false, lo, hi, g, 1.0f, out);
    }
}

// ---- k3: edge-ect only ----
__global__ __launch_bounds__(256) void edge_k(
    const float* __restrict__ x, const float* __restrict__ v,
    const float* __restrict__ lin, const int2* __restrict__ epair,
    const int* __restrict__ offs, float* __restrict__ out)
{
    const int g = blockIdx.x / CPB_E, c = blockIdx.x % CPB_E;
    const int s0 = offs[g], s1 = offs[g + 1];
    const int chunk = (s1 - s0 + CPB_E - 1) / CPB_E;
    const int lo = s0 + c * chunk;
    const int hi = min(s1, lo + chunk);
    ect_core(x, v, lin, epair, true, lo, hi, g, -1.0f, out);
}

extern "C" void kernel_launch(void* const* d_in, const int* in_sizes, int n_in,
                              void* d_out, int out_size, void* d_ws, size_t ws_size,
                              hipStream_t stream) {
    const float* x   = (const float*)d_in[0];
    const float* v   = (const float*)d_in[1];
    const float* lin = (const float*)d_in[2];
    const int* edge_index = (const int*)d_in[3];
    const int* batch = (const int*)d_in[4];

    const int N = in_sizes[0] / 3;
    const int E = in_sizes[3] / 2;
    const int* src = edge_index;       // edge_index[0][:]
    const int* dst = edge_index + E;   // edge_index[1][:]
    float* out = (float*)d_out;

    char* ws = (char*)d_ws;
    int* starts = (int*)ws;                                   // 65 ints
    int* offs   = (int*)(ws + 512);                           // 65 ints
    int* hist   = (int*)(ws + 1024);                          // NB*BB ints (16 KB)
    int* ge     = (int*)(ws + 65536);                         // E ints
    int2* epair = (int2*)(ws + 65536 + (((size_t)E * 4 + 255) / 256) * 256);  // E int2

    const int nB = (N + 255) / 256;
    prep_k<<<nB + NB, 256, 0, stream>>>(batch, src, N, E, nB, starts, hist, ge, out);
    mid_k<<<NB + BB * CPB_N, 256, 0, stream>>>(x, v, lin, src, dst, ge, E,
                                               hist, offs, epair, starts, out);
    edge_k<<<BB * CPB_E, 256, 0, stream>>>(x, v, lin, epair, offs, out);
}